// Round 8
// baseline (73.287 us; speedup 1.0000x reference)
//
#include <hip/hip_runtime.h>
#include <hip/hip_bf16.h>

#define T_LEN   200
#define NTILES  13     // ceil(200/16)

typedef __bf16 bf16x8 __attribute__((ext_vector_type(8)));
typedef __bf16 bf16x4 __attribute__((ext_vector_type(4)));
typedef float  f32x4  __attribute__((ext_vector_type(4)));

#if __has_builtin(__builtin_amdgcn_mfma_f32_16x16x16_bf16)
#define MFMA16(a, b, c) __builtin_amdgcn_mfma_f32_16x16x16_bf16((a), (b), (c), 0, 0, 0)
#elif __has_builtin(__builtin_amdgcn_mfma_f32_16x16x16bf16_1k)
#define MFMA16(a, b, c) __builtin_amdgcn_mfma_f32_16x16x16bf16_1k((a), (b), (c), 0, 0, 0)
#else
static __device__ __forceinline__ f32x4 mfma16_asm(bf16x4 a, bf16x4 b, f32x4 c) {
  asm("v_mfma_f32_16x16x16_bf16 %0, %1, %2, %0" : "+v"(c) : "v"(a), "v"(b));
  return c;
}
#define MFMA16(a, b, c) mfma16_asm((a), (b), (c))
#endif

#define MFMA32(a, b, c) __builtin_amdgcn_mfma_f32_16x16x32_bf16((a), (b), (c), 0, 0, 0)

// LDS ~19.5 KB (not occupancy-limiting). Weights staged once per block.
struct __align__(16) Smem {
  unsigned char w1ac[64 * 144];   // [j][d] bf16: W1a+W1c (stride 144B)
  unsigned char w1d [64 * 144];   // [j][d] bf16: W1d
  float biasL[4][64];             // per-wave(row) exact f32 bias1eff
};

__device__ __forceinline__ void loadA(const float* __restrict__ behB, int t, int kb,
                                      f32x4 (&x)[4]) {
  if (t < T_LEN) {
    const float* p = behB + (size_t)t * 64 + kb;
    x[0] = *(const f32x4*)p;
    x[1] = *(const f32x4*)(p + 4);
    x[2] = *(const f32x4*)(p + 32);
    x[3] = *(const f32x4*)(p + 36);
  } else {
    x[0] = f32x4{0.f, 0.f, 0.f, 0.f};
    x[1] = f32x4{0.f, 0.f, 0.f, 0.f};
    x[2] = f32x4{0.f, 0.f, 0.f, 0.f};
    x[3] = f32x4{0.f, 0.f, 0.f, 0.f};
  }
}

__global__ __launch_bounds__(256, 3) void lau_kernel(
    const float* __restrict__ behG, const float* __restrict__ candG,
    const int*  __restrict__ maskG,
    const float* __restrict__ W1g, const float* __restrict__ b1g, const float* __restrict__ a1g,
    const float* __restrict__ W2g, const float* __restrict__ b2g, const float* __restrict__ a2g,
    const float* __restrict__ W3g,
    float* __restrict__ outG)
{
  __shared__ Smem s;
  const int tid  = threadIdx.x;
  const int lane = tid & 63;
  const int wv   = tid >> 6;
  const int b    = blockIdx.x * 4 + wv;   // one wave per batch row
  const int r    = lane & 15;
  const int g    = lane >> 4;
  const int kb   = g * 8;

  const float* candB = candG + (size_t)b * 64;

  // ---- cooperative weight staging (batch-independent) ----
  for (int idx = tid; idx < 4096; idx += 256) {
    int j = idx & 63, d = idx >> 6;            // consecutive j -> coalesced
    float ac = W1g[d * 64 + j] + W1g[(128 + d) * 64 + j];
    float dd = W1g[(192 + d) * 64 + j];
    *(__bf16*)(s.w1ac + j * 144 + d * 2) = (__bf16)ac;
    *(__bf16*)(s.w1d  + j * 144 + d * 2) = (__bf16)dd;
  }
  // per-row exact f32 bias: b1 + cand @ (W1b - W1c)
  {
    float biasv = b1g[lane];
#pragma unroll 8
    for (int d = 0; d < 64; ++d) {
      float wd = W1g[(64 + d) * 64 + lane] - W1g[(128 + d) * 64 + lane];
      biasv += candB[d] * wd;
    }
    s.biasL[wv][lane] = biasv;
  }
  __syncthreads();
  // ---- waves fully independent below ----

  const bool boolmask = (__ballot(((const unsigned int*)maskG)[lane] > 1u) != 0ull);

  // ---- fold this lane's 13 mask values into a bitmask (no in-loop mask traffic) ----
  const unsigned char* maskB8 = (const unsigned char*)maskG + (size_t)b * T_LEN;
  const int* maskB32 = maskG + (size_t)b * T_LEN;
  unsigned mbits = 0;
#pragma unroll
  for (int mt = 0; mt < NTILES; ++mt) {
    int t = mt * 16 + r;
    int mv = 0;
    if (t < T_LEN) mv = boolmask ? (int)maskB8[t] : maskB32[t];
    mbits |= (mv != 0 ? 1u : 0u) << mt;
  }

  // cand chunks for this lane's d-columns
  const f32x4 c0a = *(const f32x4*)(candB + kb);
  const f32x4 c0b = *(const f32x4*)(candB + kb + 4);
  const f32x4 c1a = *(const f32x4*)(candB + kb + 32);
  const f32x4 c1b = *(const f32x4*)(candB + kb + 36);

  // loop-invariant layer-1 A-fragments: W1eff^T = (W1a+W1c) + cand_d * W1d
  bf16x8 A1[4][2];
#pragma unroll
  for (int f = 0; f < 8; ++f) {
    const int jt = f >> 1, kc = f & 1;
    const int rowoff = (jt * 16 + r) * 144 + kc * 64 + g * 16;
    bf16x8 ac = *(const bf16x8*)(s.w1ac + rowoff);
    bf16x8 dd = *(const bf16x8*)(s.w1d  + rowoff);
    f32x4 cA = kc ? c1a : c0a;
    f32x4 cB = kc ? c1b : c0b;
    bf16x8 o;
#pragma unroll
    for (int e = 0; e < 4; ++e) {
      o[e]     = (__bf16)((float)ac[e]     + cA[e] * (float)dd[e]);
      o[4 + e] = (__bf16)((float)ac[4 + e] + cB[e] * (float)dd[4 + e]);
    }
    A1[jt][kc] = o;
  }

  // layer-2 weight fragments (used as MFMA A-operand):
  // W2f[nt*4+c][i] = W2[c*16 + g*4 + i][nt*16 + r]
  bf16x4 W2f[8];
#pragma unroll
  for (int f = 0; f < 8; ++f) {
    const int nt = f >> 2, c = f & 3;
#pragma unroll
    for (int i = 0; i < 4; ++i)
      W2f[f][i] = (__bf16)W2g[(c * 16 + g * 4 + i) * 32 + nt * 16 + r];
  }

  // per-lane bias rows for layer-1 C-init: bias[j = jt*16 + g*4 + i]
  f32x4 bj4[4];
#pragma unroll
  for (int jt = 0; jt < 4; ++jt)
#pragma unroll
    for (int i = 0; i < 4; ++i)
      bj4[jt][i] = s.biasL[wv][jt * 16 + g * 4 + i];

  const float al1 = a1g[0];
  const float al2 = a2g[0];
  const f32x4 cinit0 = *(const f32x4*)(b2g + g * 4);
  const f32x4 cinit1 = *(const f32x4*)(b2g + 16 + g * 4);
  const f32x4 w3f0   = *(const f32x4*)(W3g + g * 4);
  const f32x4 w3f1   = *(const f32x4*)(W3g + 16 + g * 4);

  const float* behB = behG + (size_t)b * T_LEN * 64;

  // per-lane online-softmax state (lane owns t = mt*16 + r)
  float mrun = -__builtin_inff();
  float srun = 0.f;
  f32x4 o0 = {0,0,0,0}, o1 = {0,0,0,0}, o2 = {0,0,0,0}, o3 = {0,0,0,0};

  // depth-2 prefetch: named ping-pong buffers, prefetch distance 2
  f32x4 xa[4], xb[4];
  loadA(behB, r, kb, xa);        // tile 0
  loadA(behB, 16 + r, kb, xb);   // tile 1

#define BODY(XC, MT, PFT, DOPF) do {                                          \
    bf16x8 ab0, ab1;                                                          \
    _Pragma("unroll")                                                         \
    for (int i = 0; i < 4; ++i) {                                             \
      ab0[i]     = (__bf16)XC[0][i];                                          \
      ab0[4 + i] = (__bf16)XC[1][i];                                          \
      ab1[i]     = (__bf16)XC[2][i];                                          \
      ab1[4 + i] = (__bf16)XC[3][i];                                          \
    }                                                                         \
    if (DOPF) loadA(behB, (PFT) * 16 + r, kb, XC);                            \
    bf16x4 a2f[4];                                                            \
    _Pragma("unroll")                                                         \
    for (int jt = 0; jt < 4; ++jt) {                                          \
      f32x4 acc = MFMA32(A1[jt][0], ab0, bj4[jt]);                            \
      acc = MFMA32(A1[jt][1], ab1, acc);                                      \
      _Pragma("unroll")                                                       \
      for (int i = 0; i < 4; ++i) {                                           \
        float h = acc[i];                                                     \
        h = (h >= 0.f) ? h : al1 * h;                                         \
        a2f[jt][i] = (__bf16)h;                                               \
      }                                                                       \
    }                                                                         \
    f32x4 acc20 = cinit0, acc21 = cinit1;                                     \
    _Pragma("unroll")                                                         \
    for (int c = 0; c < 4; ++c) acc20 = MFMA16(W2f[c],     a2f[c], acc20);    \
    _Pragma("unroll")                                                         \
    for (int c = 0; c < 4; ++c) acc21 = MFMA16(W2f[4 + c], a2f[c], acc21);    \
    float partial = 0.f;                                                      \
    _Pragma("unroll")                                                         \
    for (int i = 0; i < 4; ++i) {                                             \
      float h0 = acc20[i]; h0 = (h0 >= 0.f) ? h0 : al2 * h0;                  \
      float h1 = acc21[i]; h1 = (h1 >= 0.f) ? h1 : al2 * h1;                  \
      partial += h0 * w3f0[i] + h1 * w3f1[i];                                 \
    }                                                                         \
    partial += __shfl_xor(partial, 16);                                       \
    partial += __shfl_xor(partial, 32);                                       \
    const bool valid = ((mbits >> (MT)) & 1u) != 0u;                          \
    float lvt = valid ? partial : -__builtin_inff();                          \
    if (lvt > mrun + 8.f) {                                                   \
      float fs = __expf(mrun - lvt);                                          \
      srun *= fs;                                                             \
      _Pragma("unroll")                                                       \
      for (int i = 0; i < 4; ++i) {                                           \
        o0[i] *= fs; o1[i] *= fs; o2[i] *= fs; o3[i] *= fs;                   \
      }                                                                       \
      mrun = lvt;                                                             \
    }                                                                         \
    float et = valid ? __expf(lvt - mrun) : 0.f;                              \
    srun += et;                                                               \
    _Pragma("unroll")                                                         \
    for (int i = 0; i < 4; ++i) {                                             \
      o0[i] += et * (float)ab0[i];                                            \
      o1[i] += et * (float)ab0[4 + i];                                        \
      o2[i] += et * (float)ab1[i];                                            \
      o3[i] += et * (float)ab1[4 + i];                                        \
    }                                                                         \
  } while (0)

#pragma unroll 1
  for (int mt = 0; mt < NTILES - 1; mt += 2) {
    BODY(xa, mt,     mt + 2, true);                  // mt <= 10 -> pf tile <= 12
    BODY(xb, mt + 1, mt + 3, (mt + 3) < NTILES);     // pf odd tiles <= 11
  }
  BODY(xa, NTILES - 1, 0, false);                    // tile 12

#undef BODY

  // ---- epilogue: merge the 16 per-lane states across r ----
  float M = mrun;
#pragma unroll
  for (int off = 1; off < 16; off <<= 1) M = fmaxf(M, __shfl_xor(M, off));
  {
    float fac = __expf(mrun - M);   // never-valid lane: exp(-inf)=0
    srun *= fac;
#pragma unroll
    for (int i = 0; i < 4; ++i) { o0[i] *= fac; o1[i] *= fac; o2[i] *= fac; o3[i] *= fac; }
  }
#pragma unroll
  for (int off = 1; off < 16; off <<= 1) {
#pragma unroll
    for (int i = 0; i < 4; ++i) {
      o0[i] += __shfl_xor(o0[i], off);
      o1[i] += __shfl_xor(o1[i], off);
      o2[i] += __shfl_xor(o2[i], off);
      o3[i] += __shfl_xor(o3[i], off);
    }
    srun += __shfl_xor(srun, off);
  }
  if (r == 0) {
    float inv = 1.f / srun;
    float* po = outG + (size_t)b * 64 + kb;
#pragma unroll
    for (int i = 0; i < 4; ++i) {
      o0[i] *= inv; o1[i] *= inv; o2[i] *= inv; o3[i] *= inv;
    }
    *(f32x4*)(po)      = o0;
    *(f32x4*)(po + 4)  = o1;
    *(f32x4*)(po + 32) = o2;
    *(f32x4*)(po + 36) = o3;
  }
}

extern "C" void kernel_launch(void* const* d_in, const int* in_sizes, int n_in,
                              void* d_out, int out_size, void* d_ws, size_t ws_size,
                              hipStream_t stream) {
  (void)n_in; (void)d_ws; (void)ws_size; (void)out_size;
  const float* beh  = (const float*)d_in[0];
  const float* cand = (const float*)d_in[1];
  const int*   mask = (const int*)d_in[2];
  const float* W1   = (const float*)d_in[3];
  const float* b1   = (const float*)d_in[4];
  const float* a1   = (const float*)d_in[5];
  const float* W2   = (const float*)d_in[6];
  const float* b2   = (const float*)d_in[7];
  const float* a2   = (const float*)d_in[8];
  const float* W3   = (const float*)d_in[9];
  // d_in[10] (b3): uniform additive bias cancels in softmax

  int B = in_sizes[1] / 64;   // 4096
  int grid = B / 4;           // one wave per batch row
  lau_kernel<<<grid, 256, 0, stream>>>(beh, cand, mask, W1, b1, a1, W2, b2, a2, W3,
                                       (float*)d_out);
}